// Round 1
// baseline (25.048 us; speedup 1.0000x reference)
//
#include <hip/hip_runtime.h>

// out[b,h,w,8*i+j] = x[b,h,w,i] * weight[h,w,j] + bias
// x: (32,112,112,8) f32, weight: (112,112,8) f32, bias: (1,) f32
// out: (32,112,112,64) f32
//
// One thread per output float4 (16B/lane stores, fully coalesced).
// For an aligned 4-channel output group: i = sub>>1 constant, j0 = (sub&1)*4
// -> 1 scalar x load + 1 float4 weight load (L2-resident) + 4 FMA + 1 float4 store.

#define HW_PIX (112 * 112)

__global__ __launch_bounds__(256) void mult_layer_kernel(
    const float* __restrict__ x,
    const float* __restrict__ weight,
    const float* __restrict__ bias,
    float* __restrict__ out,
    int n4) {
  int gid = blockIdx.x * blockDim.x + threadIdx.x;
  if (gid >= n4) return;

  int pix = gid >> 4;       // b*H*W + h*W + w  (16 float4-groups per pixel)
  int sub = gid & 15;       // which float4 within the 64 output channels
  int i   = sub >> 1;       // x channel (0..7)
  int j0  = (sub & 1) << 2; // weight channel base (0 or 4)
  int hw  = pix % HW_PIX;   // (h*W + w)

  float  xv = x[pix * 8 + i];
  float4 wv = *reinterpret_cast<const float4*>(weight + hw * 8 + j0);
  float  bv = bias[0];

  float4 o;
  o.x = fmaf(xv, wv.x, bv);
  o.y = fmaf(xv, wv.y, bv);
  o.z = fmaf(xv, wv.z, bv);
  o.w = fmaf(xv, wv.w, bv);

  reinterpret_cast<float4*>(out)[gid] = o;
}

extern "C" void kernel_launch(void* const* d_in, const int* in_sizes, int n_in,
                              void* d_out, int out_size, void* d_ws, size_t ws_size,
                              hipStream_t stream) {
  const float* x      = (const float*)d_in[0];
  const float* weight = (const float*)d_in[1];
  const float* bias   = (const float*)d_in[2];
  float* out          = (float*)d_out;

  int n4 = out_size / 4;                 // 6,422,528 float4 stores
  int block = 256;
  int grid = (n4 + block - 1) / block;   // 25,088 blocks
  mult_layer_kernel<<<grid, block, 0, stream>>>(x, weight, bias, out, n4);
}